// Round 2
// baseline (302.690 us; speedup 1.0000x reference)
//
#include <hip/hip_runtime.h>

#define B_ 32
#define T_ 64
#define I_ 256
#define H_ 512

static constexpr float ALPHA_F = 0.951229424500714f;   // exp(-1/20)
static constexpr float OMD_F   = 0.048770575499286f;   // 1 - decay
static constexpr float ETA_F   = 0.1f;
static constexpr float CSCALE  = 0.02f;                // 0.2 * ETA

// ---------------- Kernel 1: projection GEMM ----------------
// P[m][n] = sum_k x[m][k] * W[n][k];  M=2048, N=1024, K=256 (both row-major, K contiguous)
__global__ __launch_bounds__(256) void proj_gemm(const float* __restrict__ x,
                                                 const float* __restrict__ W,
                                                 float* __restrict__ P) {
  __shared__ float As[64][65];
  __shared__ float Bs[64][65];
  const int m0 = blockIdx.x * 64;
  const int n0 = blockIdx.y * 64;
  const int tid = threadIdx.x;
  const int ty = tid >> 4, tx = tid & 15;
  float acc[4][4] = {};
  for (int k0 = 0; k0 < I_; k0 += 64) {
#pragma unroll
    for (int e = 0; e < 16; ++e) {
      int idx = tid + e * 256;
      int r = idx >> 6, c = idx & 63;
      As[r][c] = x[(size_t)(m0 + r) * I_ + k0 + c];
      Bs[r][c] = W[(size_t)(n0 + r) * I_ + k0 + c];
    }
    __syncthreads();
#pragma unroll 8
    for (int kk = 0; kk < 64; ++kk) {
      float a[4], bb[4];
#pragma unroll
      for (int i = 0; i < 4; ++i) a[i] = As[ty * 4 + i][kk];
#pragma unroll
      for (int j = 0; j < 4; ++j) bb[j] = Bs[tx * 4 + j][kk];
#pragma unroll
      for (int i = 0; i < 4; ++i)
#pragma unroll
        for (int j = 0; j < 4; ++j) acc[i][j] += a[i] * bb[j];
    }
    __syncthreads();
  }
#pragma unroll
  for (int i = 0; i < 4; ++i) {
    float4 o = make_float4(acc[i][0], acc[i][1], acc[i][2], acc[i][3]);
    *reinterpret_cast<float4*>(&P[(size_t)(m0 + ty * 4 + i) * 1024 + n0 + tx * 4]) = o;
  }
}

// ---------------- Kernel 2: sequential scan (attention form, full fp32) ----------------
// One block per batch, 512 threads; thread h owns state kv,vv,kt,vt.
// ikv_t[h] = 0.02 * sum_{s<t} (kt_s . k_t) * vt_s[h]
// Histories kt/vt live in GLOBAL d_ws (fp32) — also consumed by mem_gemm.
__global__ __launch_bounds__(512) void scan_kernel(const float* __restrict__ proj,
                                                   float* __restrict__ keys,
                                                   float* __restrict__ vals,
                                                   float* __restrict__ ktg,
                                                   float* __restrict__ vtg) {
  const int b = blockIdx.x;
  const int h = threadIdx.x;
  const int wave = h >> 6, lane = h & 63;

  __shared__ float k_sh[H_];
  __shared__ float c_sh[T_];

  float kv = 0.f, vv = 0.f, kt = 0.f, vt = 0.f;
  const float* pk = proj + (size_t)b * T_ * 1024;
  float* ktb = ktg + (size_t)b * T_ * H_;
  float* vtb = vtg + (size_t)b * T_ * H_;

  for (int t = 0; t < T_; ++t) {
    // ---- Phase A: kv update, k = tanh(kv) ----
    float ik = pk[(size_t)t * 1024 + h];
    kv = ALPHA_F * kv + ik;
    float k = tanhf(kv);
    k_sh[h] = k;
    __syncthreads();   // k_sh ready; also fences prev step's ktb stores vs Phase B loads

    // ---- Phase B: dots c_s = 0.02 * (kt_s . k), wave w handles s = w, w+8, ... ----
    if (t > 0) {
      float4 kr0 = *reinterpret_cast<const float4*>(&k_sh[4 * lane]);
      float4 kr1 = *reinterpret_cast<const float4*>(&k_sh[4 * lane + 256]);
      for (int s = wave; s < t; s += 8) {
        const float* kr = ktb + (size_t)s * H_;
        float4 a0 = *reinterpret_cast<const float4*>(kr + 4 * lane);
        float4 a1 = *reinterpret_cast<const float4*>(kr + 4 * lane + 256);
        float p = a0.x * kr0.x + a0.y * kr0.y + a0.z * kr0.z + a0.w * kr0.w
                + a1.x * kr1.x + a1.y * kr1.y + a1.z * kr1.z + a1.w * kr1.w;
#pragma unroll
        for (int m = 1; m < 64; m <<= 1) p += __shfl_xor(p, m);
        if (lane == 0) c_sh[s] = CSCALE * p;
      }
    }
    __syncthreads();   // c_sh ready

    // ---- Phase C: ikv = sum_{s<t} c_s * vt_s[h]  (vt history = own prior stores) ----
    float ikv = 0.f;
    {
      const float* vh = vtb + h;
#pragma unroll
      for (int s0 = 0; s0 < T_; s0 += 8) {
        if (s0 + 8 <= t) {           // t is wave-uniform -> scalar branch
          float cq[8], vq[8];
#pragma unroll
          for (int q = 0; q < 8; ++q) {
            cq[q] = c_sh[s0 + q];
            vq[q] = vh[(size_t)(s0 + q) * H_];
          }
#pragma unroll
          for (int q = 0; q < 8; ++q) ikv += cq[q] * vq[q];
        } else if (s0 < t) {
#pragma unroll
          for (int q = 0; q < 8; ++q)
            if (s0 + q < t) ikv += c_sh[s0 + q] * vh[(size_t)(s0 + q) * H_];
        }
      }
    }

    float iv = pk[(size_t)t * 1024 + 512 + h];
    vv = ALPHA_F * vv + iv + ikv;
    float v = tanhf(vv);
    kt = ALPHA_F * kt + OMD_F * k;
    vt = ALPHA_F * vt + OMD_F * v;

    ktb[(size_t)t * H_ + h] = kt;
    vtb[(size_t)t * H_ + h] = vt;

    size_t go = ((size_t)b * T_ + t) * H_ + h;
    keys[go] = k;
    vals[go] = v;
    // next Phase A's __syncthreads fences these stores before Phase B's loads
  }
}

// ---------------- Kernel 3: mem = ETA * vt_hist^T @ kt_hist (per batch, K=T=64) ----------------
__global__ __launch_bounds__(256) void mem_gemm(const float* __restrict__ vtg,
                                                const float* __restrict__ ktg,
                                                float* __restrict__ mem) {
  const int b = blockIdx.z;
  const int i0 = blockIdx.y * 64;
  const int j0 = blockIdx.x * 64;
  __shared__ float Vs[64][65];  // [t][i]
  __shared__ float Ks[64][65];  // [t][j]
  const int tid = threadIdx.x;
  const int ty = tid >> 4, tx = tid & 15;
  const float* vb = vtg + (size_t)b * T_ * H_;
  const float* kb = ktg + (size_t)b * T_ * H_;
#pragma unroll
  for (int e = 0; e < 16; ++e) {
    int idx = tid + e * 256;
    int t = idx >> 6, c = idx & 63;
    Vs[t][c] = vb[(size_t)t * H_ + i0 + c];
    Ks[t][c] = kb[(size_t)t * H_ + j0 + c];
  }
  __syncthreads();
  float acc[4][4] = {};
#pragma unroll 8
  for (int t = 0; t < 64; ++t) {
    float a[4], bb[4];
#pragma unroll
    for (int i = 0; i < 4; ++i) a[i] = Vs[t][ty * 4 + i];
#pragma unroll
    for (int j = 0; j < 4; ++j) bb[j] = Ks[t][tx * 4 + j];
#pragma unroll
    for (int i = 0; i < 4; ++i)
#pragma unroll
      for (int j = 0; j < 4; ++j) acc[i][j] += a[i] * bb[j];
  }
  float* mb = mem + (size_t)b * H_ * H_;
#pragma unroll
  for (int i = 0; i < 4; ++i) {
    float4 o = make_float4(ETA_F * acc[i][0], ETA_F * acc[i][1],
                           ETA_F * acc[i][2], ETA_F * acc[i][3]);
    *reinterpret_cast<float4*>(&mb[(size_t)(i0 + ty * 4 + i) * H_ + j0 + tx * 4]) = o;
  }
}

extern "C" void kernel_launch(void* const* d_in, const int* in_sizes, int n_in,
                              void* d_out, int out_size, void* d_ws, size_t ws_size,
                              hipStream_t stream) {
  const float* x = (const float*)d_in[0];   // (B,T,I)
  const float* W = (const float*)d_in[1];   // (2H,I)
  float* out = (float*)d_out;
  float* mem  = out;                             // B*H*H = 8388608
  float* keys = out + (size_t)B_ * H_ * H_;      // B*T*H = 1048576
  float* vals = keys + (size_t)B_ * T_ * H_;

  // proj (B*T x 1024 = 2.1M floats) parked in mem region; consumed by scan
  // before mem_gemm overwrites it (stream-ordered).
  float* proj = mem;
  // fp32 kt/vt history in workspace (8 MB)
  float* ktg = (float*)d_ws;
  float* vtg = ktg + (size_t)B_ * T_ * H_;

  proj_gemm<<<dim3(32, 16), 256, 0, stream>>>(x, W, proj);
  scan_kernel<<<dim3(B_), 512, 0, stream>>>(proj, keys, vals, ktg, vtg);
  mem_gemm<<<dim3(8, 8, B_), 256, 0, stream>>>(vtg, ktg, mem);
}

// Round 3
// 290.464 us; speedup vs baseline: 1.0421x; 1.0421x over previous
//
#include <hip/hip_runtime.h>

#define B_ 32
#define T_ 64
#define I_ 256
#define H_ 512

static constexpr float ALPHA_F = 0.951229424500714f;   // exp(-1/20)
static constexpr float OMD_F   = 0.048770575499286f;   // 1 - decay
static constexpr float ETA_F   = 0.1f;
static constexpr float CSCALE  = 0.02f;                // 0.2 * ETA

// ---------------- Kernel 1: projection GEMM ----------------
// P[m][n] = sum_k x[m][k] * W[n][k];  M=2048, N=1024, K=256 (both row-major, K contiguous)
__global__ __launch_bounds__(256) void proj_gemm(const float* __restrict__ x,
                                                 const float* __restrict__ W,
                                                 float* __restrict__ P) {
  __shared__ float As[64][65];
  __shared__ float Bs[64][65];
  const int m0 = blockIdx.x * 64;
  const int n0 = blockIdx.y * 64;
  const int tid = threadIdx.x;
  const int ty = tid >> 4, tx = tid & 15;
  float acc[4][4] = {};
  for (int k0 = 0; k0 < I_; k0 += 64) {
#pragma unroll
    for (int e = 0; e < 16; ++e) {
      int idx = tid + e * 256;
      int r = idx >> 6, c = idx & 63;
      As[r][c] = x[(size_t)(m0 + r) * I_ + k0 + c];
      Bs[r][c] = W[(size_t)(n0 + r) * I_ + k0 + c];
    }
    __syncthreads();
#pragma unroll 8
    for (int kk = 0; kk < 64; ++kk) {
      float a[4], bb[4];
#pragma unroll
      for (int i = 0; i < 4; ++i) a[i] = As[ty * 4 + i][kk];
#pragma unroll
      for (int j = 0; j < 4; ++j) bb[j] = Bs[tx * 4 + j][kk];
#pragma unroll
      for (int i = 0; i < 4; ++i)
#pragma unroll
        for (int j = 0; j < 4; ++j) acc[i][j] += a[i] * bb[j];
    }
    __syncthreads();
  }
#pragma unroll
  for (int i = 0; i < 4; ++i) {
    float4 o = make_float4(acc[i][0], acc[i][1], acc[i][2], acc[i][3]);
    *reinterpret_cast<float4*>(&P[(size_t)(m0 + ty * 4 + i) * 1024 + n0 + tx * 4]) = o;
  }
}

// ---------------- Kernel 2: sequential scan (attention form, fp32) ----------------
// One block per batch, 512 threads; thread h owns state kv,vv,kt,vt.
// ikv_t[h] = 0.02 * sum_{s<t} (kt_s . k_t) * vt_s[h]
// kt history: LDS fp32 [64][512] (zero-init -> branch-free Phase B).
// vt history: persistent registers vq[64] (compile-time indices only).
__global__ __launch_bounds__(512) void scan_kernel(const float* __restrict__ proj,
                                                   float* __restrict__ keys,
                                                   float* __restrict__ vals,
                                                   float* __restrict__ ktg,
                                                   float* __restrict__ vtg) {
  extern __shared__ float smem[];
  float* ktL  = smem;           // [64][512] fp32, 128 KB
  float* k_sh = smem + 32768;   // [512]
  float* c_sh = smem + 33280;   // [64]

  const int b = blockIdx.x;
  const int h = threadIdx.x;
  const int wave = h >> 6, lane = h & 63;

  // zero-init kt history (rows >= t read as 0 -> dots contribute 0)
#pragma unroll
  for (int e = 0; e < 16; ++e)
    *reinterpret_cast<float4*>(&ktL[h * 64 + e * 4]) = make_float4(0.f, 0.f, 0.f, 0.f);

  float kv = 0.f, vv = 0.f, kt = 0.f, vt = 0.f;
  float vq[T_];
#pragma unroll
  for (int s = 0; s < T_; ++s) vq[s] = 0.f;

  const float* pk  = proj + (size_t)b * T_ * 1024 + h;
  float* ktb = ktg  + (size_t)b * T_ * H_ + h;
  float* vtb = vtg  + (size_t)b * T_ * H_ + h;
  float* kb2 = keys + (size_t)b * T_ * H_ + h;
  float* vb2 = vals + (size_t)b * T_ * H_ + h;

  float ik_cur = pk[0];
  float iv_cur = pk[512];

  for (int t = 0; t < T_; ++t) {
    // prefetch next step's projections (hidden under this step's B/C)
    float ik_nxt = 0.f, iv_nxt = 0.f;
    if (t + 1 < T_) {
      ik_nxt = pk[(size_t)(t + 1) * 1024];
      iv_nxt = pk[(size_t)(t + 1) * 1024 + 512];
    }

    // ---- Phase A ----
    kv = ALPHA_F * kv + ik_cur;
    float k = tanhf(kv);
    k_sh[h] = k;
    kb2[(size_t)t * H_] = k;     // keys out, off critical path
    __syncthreads();             // k_sh ready; prev step's ktL row fenced

    // ---- Phase B: c_s = 0.02 * (kt_s . k), branch-free; wave w owns rows 8w..8w+7 ----
    float4 kr0 = *reinterpret_cast<const float4*>(&k_sh[4 * lane]);
    float4 kr1 = *reinterpret_cast<const float4*>(&k_sh[4 * lane + 256]);
#pragma unroll
    for (int j = 0; j < 8; ++j) {
      const int s = wave * 8 + j;
      const float* kr = &ktL[(size_t)s * H_ + 4 * lane];
      float4 a0 = *reinterpret_cast<const float4*>(kr);
      float4 a1 = *reinterpret_cast<const float4*>(kr + 256);
      float p = a0.x * kr0.x + a0.y * kr0.y + a0.z * kr0.z + a0.w * kr0.w
              + a1.x * kr1.x + a1.y * kr1.y + a1.z * kr1.z + a1.w * kr1.w;
#pragma unroll
      for (int m = 1; m < 64; m <<= 1) p += __shfl_xor(p, m);
      if (lane == 0) c_sh[s] = CSCALE * p;
    }
    __syncthreads();             // c_sh ready (all 64 entries written every step)

    // ---- Phase C: ikv = sum_s c_s * vq[s]  (registers + broadcast c reads) ----
    float p0 = 0.f, p1 = 0.f, p2 = 0.f, p3 = 0.f;
#pragma unroll
    for (int q = 0; q < 16; ++q) {
      float4 c4 = *reinterpret_cast<const float4*>(&c_sh[4 * q]);
      p0 += c4.x * vq[4 * q + 0];
      p1 += c4.y * vq[4 * q + 1];
      p2 += c4.z * vq[4 * q + 2];
      p3 += c4.w * vq[4 * q + 3];
    }
    float ikv = (p0 + p1) + (p2 + p3);

    vv = ALPHA_F * vv + iv_cur + ikv;
    float v = tanhf(vv);
    kt = ALPHA_F * kt + OMD_F * k;
    vt = ALPHA_F * vt + OMD_F * v;

    ktL[(size_t)t * H_ + h] = kt;          // LDS history (fenced by next Phase A barrier)
#pragma unroll
    for (int s = 0; s < T_; ++s)           // vq[t] = vt without runtime indexing
      vq[s] = (s == t) ? vt : vq[s];

    vb2[(size_t)t * H_] = v;
    ktb[(size_t)t * H_] = kt;
    vtb[(size_t)t * H_] = vt;

    ik_cur = ik_nxt;
    iv_cur = iv_nxt;
  }
}

// ---------------- Kernel 3: mem = ETA * vt_hist^T @ kt_hist (per batch, K=T=64) ----------------
__global__ __launch_bounds__(256) void mem_gemm(const float* __restrict__ vtg,
                                                const float* __restrict__ ktg,
                                                float* __restrict__ mem) {
  const int b = blockIdx.z;
  const int i0 = blockIdx.y * 64;
  const int j0 = blockIdx.x * 64;
  __shared__ float Vs[64][65];  // [t][i]
  __shared__ float Ks[64][65];  // [t][j]
  const int tid = threadIdx.x;
  const int ty = tid >> 4, tx = tid & 15;
  const float* vb = vtg + (size_t)b * T_ * H_;
  const float* kb = ktg + (size_t)b * T_ * H_;
#pragma unroll
  for (int e = 0; e < 16; ++e) {
    int idx = tid + e * 256;
    int t = idx >> 6, c = idx & 63;
    Vs[t][c] = vb[(size_t)t * H_ + i0 + c];
    Ks[t][c] = kb[(size_t)t * H_ + j0 + c];
  }
  __syncthreads();
  float acc[4][4] = {};
#pragma unroll 8
  for (int t = 0; t < 64; ++t) {
    float a[4], bb[4];
#pragma unroll
    for (int i = 0; i < 4; ++i) a[i] = Vs[t][ty * 4 + i];
#pragma unroll
    for (int j = 0; j < 4; ++j) bb[j] = Ks[t][tx * 4 + j];
#pragma unroll
    for (int i = 0; i < 4; ++i)
#pragma unroll
      for (int j = 0; j < 4; ++j) acc[i][j] += a[i] * bb[j];
  }
  float* mb = mem + (size_t)b * H_ * H_;
#pragma unroll
  for (int i = 0; i < 4; ++i) {
    float4 o = make_float4(ETA_F * acc[i][0], ETA_F * acc[i][1],
                           ETA_F * acc[i][2], ETA_F * acc[i][3]);
    *reinterpret_cast<float4*>(&mb[(size_t)(i0 + ty * 4 + i) * H_ + j0 + tx * 4]) = o;
  }
}

extern "C" void kernel_launch(void* const* d_in, const int* in_sizes, int n_in,
                              void* d_out, int out_size, void* d_ws, size_t ws_size,
                              hipStream_t stream) {
  const float* x = (const float*)d_in[0];   // (B,T,I)
  const float* W = (const float*)d_in[1];   // (2H,I)
  float* out = (float*)d_out;
  float* mem  = out;                             // B*H*H = 8388608
  float* keys = out + (size_t)B_ * H_ * H_;      // B*T*H = 1048576
  float* vals = keys + (size_t)B_ * T_ * H_;

  // proj (B*T x 1024 = 2.1M floats) parked in mem region; consumed by scan
  // before mem_gemm overwrites it (stream-ordered).
  float* proj = mem;
  // fp32 kt/vt history in workspace (8 MB)
  float* ktg = (float*)d_ws;
  float* vtg = ktg + (size_t)B_ * T_ * H_;

  // scan needs 133376 B dynamic LDS (>64 KB default cap) — raise the cap.
  static int lds_bytes = 133376;
  (void)hipFuncSetAttribute((const void*)scan_kernel,
                            hipFuncAttributeMaxDynamicSharedMemorySize, lds_bytes);

  proj_gemm<<<dim3(32, 16), 256, 0, stream>>>(x, W, proj);
  scan_kernel<<<dim3(B_), 512, (size_t)lds_bytes, stream>>>(proj, keys, vals, ktg, vtg);
  mem_gemm<<<dim3(8, 8, B_), 256, 0, stream>>>(vtg, ktg, mem);
}

// Round 5
// 170.167 us; speedup vs baseline: 1.7788x; 1.7069x over previous
//
#include <hip/hip_runtime.h>

#define B_ 32
#define T_ 64
#define I_ 256
#define H_ 512

static constexpr float ALPHA_F = 0.951229424500714f;   // exp(-1/20)
static constexpr float OMD_F   = 0.048770575499286f;   // 1 - decay
static constexpr float ETA_F   = 0.1f;
static constexpr float CSCALE  = 0.02f;                // 0.2 * ETA

// ---------------- fast tanh: exact at saturation, ~1e-6 rel elsewhere ----------------
__device__ __forceinline__ float tanh_fast(float x) {
  float xc = fminf(fmaxf(x, -15.f), 15.f);
  float e = __expf(2.f * xc);                       // v_exp_f32 path
  return (e - 1.f) * __builtin_amdgcn_rcpf(e + 1.f);
}

// ---------------- DPP full-wave (64-lane) sum; valid result in lane 63 ----------------
template <int CTRL>
__device__ __forceinline__ float dpp_add(float x) {
  int mv = __builtin_amdgcn_update_dpp(0, __float_as_int(x), CTRL, 0xF, 0xF, true);
  return x + __int_as_float(mv);
}
__device__ __forceinline__ float wave_sum_dpp(float x) {
  x = dpp_add<0x111>(x);  // row_shr:1
  x = dpp_add<0x112>(x);  // row_shr:2
  x = dpp_add<0x114>(x);  // row_shr:4
  x = dpp_add<0x118>(x);  // row_shr:8   -> lane15/31/47/63 hold row sums
  x = dpp_add<0x142>(x);  // row_bcast:15 -> lane31 += lane15-sum, etc.
  x = dpp_add<0x143>(x);  // row_bcast:31 -> lane63 = full 64-lane sum
  return x;
}

// ---------------- Kernel 1: projection GEMM ----------------
// P[m][n] = sum_k x[m][k] * W[n][k];  M=2048, N=1024, K=256
__global__ __launch_bounds__(256) void proj_gemm(const float* __restrict__ x,
                                                 const float* __restrict__ W,
                                                 float* __restrict__ P) {
  __shared__ float As[64][65];
  __shared__ float Bs[64][65];
  const int m0 = blockIdx.x * 64;
  const int n0 = blockIdx.y * 64;
  const int tid = threadIdx.x;
  const int ty = tid >> 4, tx = tid & 15;
  float acc[4][4] = {};
  for (int k0 = 0; k0 < I_; k0 += 64) {
#pragma unroll
    for (int e = 0; e < 16; ++e) {
      int idx = tid + e * 256;
      int r = idx >> 6, c = idx & 63;
      As[r][c] = x[(size_t)(m0 + r) * I_ + k0 + c];
      Bs[r][c] = W[(size_t)(n0 + r) * I_ + k0 + c];
    }
    __syncthreads();
#pragma unroll 8
    for (int kk = 0; kk < 64; ++kk) {
      float a[4], bb[4];
#pragma unroll
      for (int i = 0; i < 4; ++i) a[i] = As[ty * 4 + i][kk];
#pragma unroll
      for (int j = 0; j < 4; ++j) bb[j] = Bs[tx * 4 + j][kk];
#pragma unroll
      for (int i = 0; i < 4; ++i)
#pragma unroll
        for (int j = 0; j < 4; ++j) acc[i][j] += a[i] * bb[j];
    }
    __syncthreads();
  }
#pragma unroll
  for (int i = 0; i < 4; ++i) {
    float4 o = make_float4(acc[i][0], acc[i][1], acc[i][2], acc[i][3]);
    *reinterpret_cast<float4*>(&P[(size_t)(m0 + ty * 4 + i) * 1024 + n0 + tx * 4]) = o;
  }
}

// ---------------- Kernel 2: sequential scan (attention form, fp32) ----------------
// One block per batch, 512 threads; thread h owns state kv,vv,kt,vt.
// ikv_t[h] = 0.02 * sum_{s<t} (kt_s . k_t) * vt_s[h]
// kt history: LDS fp32 [64][512]; vt history: registers vq[64].
#define CASE_SET(S) case S: vq[S] = vt; break;
__global__ __launch_bounds__(512, 2) void scan_kernel(const float* __restrict__ proj,
                                                      float* __restrict__ keys,
                                                      float* __restrict__ vals,
                                                      float* __restrict__ ktg,
                                                      float* __restrict__ vtg) {
  extern __shared__ float smem[];
  float* ktL  = smem;           // [64][512] fp32, 128 KB
  float* k_sh = smem + 32768;   // [512]
  float* c_sh = smem + 33280;   // [64]

  const int b = blockIdx.x;
  const int h = threadIdx.x;
  const int wave = h >> 6, lane = h & 63;

  float kv = 0.f, vv = 0.f, kt = 0.f, vt = 0.f;
  float vq[T_];
#pragma unroll
  for (int s = 0; s < T_; ++s) vq[s] = 0.f;

  const float* pk  = proj + (size_t)b * T_ * 1024 + h;
  float* ktb = ktg  + (size_t)b * T_ * H_ + h;
  float* vtb = vtg  + (size_t)b * T_ * H_ + h;
  float* kb2 = keys + (size_t)b * T_ * H_ + h;
  float* vb2 = vals + (size_t)b * T_ * H_ + h;

  float ik_cur = pk[0];
  float iv_cur = pk[512];

  for (int t = 0; t < T_; ++t) {
    // ---- Phase A ----
    kv = ALPHA_F * kv + ik_cur;
    float k = tanh_fast(kv);
    k_sh[h] = k;
    __syncthreads();                                // B1 (drains prev step's stores: far away)

    // post-barrier: output store + next-step prefetch (drain at B2, hidden under Phase B)
    kb2[(size_t)t * H_] = k;
    float ik_nxt = 0.f, iv_nxt = 0.f;
    if (t + 1 < T_) {
      ik_nxt = pk[(size_t)(t + 1) * 1024];
      iv_nxt = pk[(size_t)(t + 1) * 1024 + 512];
    }

    // ---- Phase B: c_s = 0.02*(kt_s . k); wave w owns s = 8w..8w+7; DPP reduce ----
    float4 kr0 = *reinterpret_cast<const float4*>(&k_sh[4 * lane]);
    float4 kr1 = *reinterpret_cast<const float4*>(&k_sh[4 * lane + 256]);
#pragma unroll
    for (int j = 0; j < 8; ++j) {
      const int s = wave * 8 + j;
      if (s < t) {                                  // wave-uniform scalar branch
        const float* kr = &ktL[(size_t)s * H_ + 4 * lane];
        float4 a0 = *reinterpret_cast<const float4*>(kr);
        float4 a1 = *reinterpret_cast<const float4*>(kr + 256);
        float p = a0.x * kr0.x + a0.y * kr0.y + a0.z * kr0.z + a0.w * kr0.w
                + a1.x * kr1.x + a1.y * kr1.y + a1.z * kr1.z + a1.w * kr1.w;
        p = wave_sum_dpp(p);
        if (lane == 63) c_sh[s] = CSCALE * p;
      }
    }
    __syncthreads();                                // B2

    // ---- Phase C: ikv = sum_{s<t} c_s * vq[s]  (vq[s>=t] == 0) ----
    float p0 = 0.f, p1 = 0.f, p2 = 0.f, p3 = 0.f;
#pragma unroll
    for (int q = 0; q < 16; ++q) {
      if (4 * q < t) {                              // wave-uniform
        float4 c4 = *reinterpret_cast<const float4*>(&c_sh[4 * q]);
        p0 += c4.x * vq[4 * q + 0];
        p1 += c4.y * vq[4 * q + 1];
        p2 += c4.z * vq[4 * q + 2];
        p3 += c4.w * vq[4 * q + 3];
      }
    }
    float ikv = (p0 + p1) + (p2 + p3);

    vv = ALPHA_F * vv + iv_cur + ikv;
    float v = tanh_fast(vv);
    kt = ALPHA_F * kt + OMD_F * k;
    vt = ALPHA_F * vt + OMD_F * v;

    ktL[(size_t)t * H_ + h] = kt;                   // fenced by next B1

    switch (t) {                                    // vq[t] = vt, compile-time indices
      CASE_SET(0)  CASE_SET(1)  CASE_SET(2)  CASE_SET(3)
      CASE_SET(4)  CASE_SET(5)  CASE_SET(6)  CASE_SET(7)
      CASE_SET(8)  CASE_SET(9)  CASE_SET(10) CASE_SET(11)
      CASE_SET(12) CASE_SET(13) CASE_SET(14) CASE_SET(15)
      CASE_SET(16) CASE_SET(17) CASE_SET(18) CASE_SET(19)
      CASE_SET(20) CASE_SET(21) CASE_SET(22) CASE_SET(23)
      CASE_SET(24) CASE_SET(25) CASE_SET(26) CASE_SET(27)
      CASE_SET(28) CASE_SET(29) CASE_SET(30) CASE_SET(31)
      CASE_SET(32) CASE_SET(33) CASE_SET(34) CASE_SET(35)
      CASE_SET(36) CASE_SET(37) CASE_SET(38) CASE_SET(39)
      CASE_SET(40) CASE_SET(41) CASE_SET(42) CASE_SET(43)
      CASE_SET(44) CASE_SET(45) CASE_SET(46) CASE_SET(47)
      CASE_SET(48) CASE_SET(49) CASE_SET(50) CASE_SET(51)
      CASE_SET(52) CASE_SET(53) CASE_SET(54) CASE_SET(55)
      CASE_SET(56) CASE_SET(57) CASE_SET(58) CASE_SET(59)
      CASE_SET(60) CASE_SET(61) CASE_SET(62) CASE_SET(63)
    }

    vb2[(size_t)t * H_] = v;
    ktb[(size_t)t * H_] = kt;
    vtb[(size_t)t * H_] = vt;

    ik_cur = ik_nxt;
    iv_cur = iv_nxt;
  }
}

// ---------------- Kernel 3: mem = ETA * vt_hist^T @ kt_hist (per batch, K=T=64) ----------------
__global__ __launch_bounds__(256) void mem_gemm(const float* __restrict__ vtg,
                                                const float* __restrict__ ktg,
                                                float* __restrict__ mem) {
  const int b = blockIdx.z;
  const int i0 = blockIdx.y * 64;
  const int j0 = blockIdx.x * 64;
  __shared__ float Vs[64][65];  // [t][i]
  __shared__ float Ks[64][65];  // [t][j]
  const int tid = threadIdx.x;
  const int ty = tid >> 4, tx = tid & 15;
  const float* vb = vtg + (size_t)b * T_ * H_;
  const float* kb = ktg + (size_t)b * T_ * H_;
#pragma unroll
  for (int e = 0; e < 16; ++e) {
    int idx = tid + e * 256;
    int t = idx >> 6, c = idx & 63;
    Vs[t][c] = vb[(size_t)t * H_ + i0 + c];
    Ks[t][c] = kb[(size_t)t * H_ + j0 + c];
  }
  __syncthreads();
  float acc[4][4] = {};
#pragma unroll 8
  for (int t = 0; t < 64; ++t) {
    float a[4], bb[4];
#pragma unroll
    for (int i = 0; i < 4; ++i) a[i] = Vs[t][ty * 4 + i];
#pragma unroll
    for (int j = 0; j < 4; ++j) bb[j] = Ks[t][tx * 4 + j];
#pragma unroll
    for (int i = 0; i < 4; ++i)
#pragma unroll
      for (int j = 0; j < 4; ++j) acc[i][j] += a[i] * bb[j];
  }
  float* mb = mem + (size_t)b * H_ * H_;
#pragma unroll
  for (int i = 0; i < 4; ++i) {
    float4 o = make_float4(ETA_F * acc[i][0], ETA_F * acc[i][1],
                           ETA_F * acc[i][2], ETA_F * acc[i][3]);
    *reinterpret_cast<float4*>(&mb[(size_t)(i0 + ty * 4 + i) * H_ + j0 + tx * 4]) = o;
  }
}

extern "C" void kernel_launch(void* const* d_in, const int* in_sizes, int n_in,
                              void* d_out, int out_size, void* d_ws, size_t ws_size,
                              hipStream_t stream) {
  const float* x = (const float*)d_in[0];   // (B,T,I)
  const float* W = (const float*)d_in[1];   // (2H,I)
  float* out = (float*)d_out;
  float* mem  = out;                             // B*H*H
  float* keys = out + (size_t)B_ * H_ * H_;      // B*T*H
  float* vals = keys + (size_t)B_ * T_ * H_;

  // proj parked in mem region; consumed by scan before mem_gemm overwrites it.
  float* proj = mem;
  float* ktg = (float*)d_ws;
  float* vtg = ktg + (size_t)B_ * T_ * H_;

  static int lds_bytes = 133376;
  (void)hipFuncSetAttribute((const void*)scan_kernel,
                            hipFuncAttributeMaxDynamicSharedMemorySize, lds_bytes);

  proj_gemm<<<dim3(32, 16), 256, 0, stream>>>(x, W, proj);
  scan_kernel<<<dim3(B_), 512, (size_t)lds_bytes, stream>>>(proj, keys, vals, ktg, vtg);
  mem_gemm<<<dim3(8, 8, B_), 256, 0, stream>>>(vtg, ktg, mem);
}

// Round 6
// 160.520 us; speedup vs baseline: 1.8857x; 1.0601x over previous
//
#include <hip/hip_runtime.h>

#define B_ 32
#define T_ 64
#define I_ 256
#define H_ 512

static constexpr float ALPHA_F = 0.951229424500714f;   // exp(-1/20)
static constexpr float OMD_F   = 0.048770575499286f;   // 1 - decay
static constexpr float ETA_F   = 0.1f;
static constexpr float CSCALE  = 0.02f;                // 0.2 * ETA

// ---------------- fast tanh: exact at saturation, ~1e-6 rel elsewhere ----------------
__device__ __forceinline__ float tanh_fast(float x) {
  float xc = fminf(fmaxf(x, -15.f), 15.f);
  float e = __expf(2.f * xc);                       // v_exp_f32 path
  return (e - 1.f) * __builtin_amdgcn_rcpf(e + 1.f);
}

// ---------------- DPP full-wave (64-lane) sum; valid result in lane 63 ----------------
template <int CTRL>
__device__ __forceinline__ float dpp_add(float x) {
  int mv = __builtin_amdgcn_update_dpp(0, __float_as_int(x), CTRL, 0xF, 0xF, true);
  return x + __int_as_float(mv);
}
__device__ __forceinline__ float wave_sum_dpp(float x) {
  x = dpp_add<0x111>(x);  // row_shr:1
  x = dpp_add<0x112>(x);  // row_shr:2
  x = dpp_add<0x114>(x);  // row_shr:4
  x = dpp_add<0x118>(x);  // row_shr:8   -> lane15/31/47/63 hold row sums
  x = dpp_add<0x142>(x);  // row_bcast:15
  x = dpp_add<0x143>(x);  // row_bcast:31 -> lane63 = full 64-lane sum
  return x;
}

// ---------------- Kernel 1: projection GEMM ----------------
__global__ __launch_bounds__(256) void proj_gemm(const float* __restrict__ x,
                                                 const float* __restrict__ W,
                                                 float* __restrict__ P) {
  __shared__ float As[64][65];
  __shared__ float Bs[64][65];
  const int m0 = blockIdx.x * 64;
  const int n0 = blockIdx.y * 64;
  const int tid = threadIdx.x;
  const int ty = tid >> 4, tx = tid & 15;
  float acc[4][4] = {};
  for (int k0 = 0; k0 < I_; k0 += 64) {
#pragma unroll
    for (int e = 0; e < 16; ++e) {
      int idx = tid + e * 256;
      int r = idx >> 6, c = idx & 63;
      As[r][c] = x[(size_t)(m0 + r) * I_ + k0 + c];
      Bs[r][c] = W[(size_t)(n0 + r) * I_ + k0 + c];
    }
    __syncthreads();
#pragma unroll 8
    for (int kk = 0; kk < 64; ++kk) {
      float a[4], bb[4];
#pragma unroll
      for (int i = 0; i < 4; ++i) a[i] = As[ty * 4 + i][kk];
#pragma unroll
      for (int j = 0; j < 4; ++j) bb[j] = Bs[tx * 4 + j][kk];
#pragma unroll
      for (int i = 0; i < 4; ++i)
#pragma unroll
        for (int j = 0; j < 4; ++j) acc[i][j] += a[i] * bb[j];
    }
    __syncthreads();
  }
#pragma unroll
  for (int i = 0; i < 4; ++i) {
    float4 o = make_float4(acc[i][0], acc[i][1], acc[i][2], acc[i][3]);
    *reinterpret_cast<float4*>(&P[(size_t)(m0 + ty * 4 + i) * 1024 + n0 + tx * 4]) = o;
  }
}

// ---------------- Kernel 2: sequential scan (attention form, fp32) ----------------
// One block per batch, 512 threads; thread h owns state kv,vv,kt,vt.
// ikv_t[h] = 0.02 * sum_{s<t} (kt_s . k_t) * vt_s[h]
// kt history: LDS fp32 [64][512] ZERO-INIT (branch-free everywhere).
// vt history: registers vq[64] (vq[s>=t] == 0).
#define CASE_SET(S) case S: vq[S] = vt; break;
__global__ __launch_bounds__(512, 2) void scan_kernel(const float* __restrict__ proj,
                                                      float* __restrict__ keys,
                                                      float* __restrict__ vals,
                                                      float* __restrict__ ktg,
                                                      float* __restrict__ vtg) {
  extern __shared__ float smem[];
  float* ktL  = smem;           // [64][512] fp32, 128 KB
  float* k_sh = smem + 32768;   // [512]
  float* c_sh = smem + 33280;   // [64]

  const int b = blockIdx.x;
  const int h = threadIdx.x;
  const int wave = h >> 6, lane = h & 63;

  // zero-init kt history: rows >= t read as 0 -> dots = 0 -> c_sh = 0
#pragma unroll
  for (int e = 0; e < 16; ++e)
    *reinterpret_cast<float4*>(&ktL[h * 64 + e * 4]) = make_float4(0.f, 0.f, 0.f, 0.f);

  float kv = 0.f, vv = 0.f, kt = 0.f, vt = 0.f;
  float vq[T_];
#pragma unroll
  for (int s = 0; s < T_; ++s) vq[s] = 0.f;

  const float* pk  = proj + (size_t)b * T_ * 1024 + h;
  float* ktb = ktg  + (size_t)b * T_ * H_ + h;
  float* vtb = vtg  + (size_t)b * T_ * H_ + h;
  float* kb2 = keys + (size_t)b * T_ * H_ + h;
  float* vb2 = vals + (size_t)b * T_ * H_ + h;

  float ik_cur = pk[0];
  float iv_cur = pk[512];
  float v_r = 0.f, kt_r = 0.f, vt_r = 0.f;   // prev-step values carried for deferred store

  for (int t = 0; t < T_; ++t) {
    // ---- Phase A ----
    kv = ALPHA_F * kv + ik_cur;
    float k = tanh_fast(kv);
    k_sh[h] = k;
    __syncthreads();                                // B1 (prev stores had a full step to drain)

    // post-B1: all 4 global stores + prefetch issue here; drain hides under Phase B
    kb2[(size_t)t * H_] = k;
    if (t > 0) {                                    // wave-uniform
      vb2[(size_t)(t - 1) * H_] = v_r;
      ktb[(size_t)(t - 1) * H_] = kt_r;
      vtb[(size_t)(t - 1) * H_] = vt_r;
    }
    float ik_nxt = 0.f, iv_nxt = 0.f;
    if (t + 1 < T_) {
      ik_nxt = pk[(size_t)(t + 1) * 1024];
      iv_nxt = pk[(size_t)(t + 1) * 1024 + 512];
    }

    // ---- Phase B: branch-free; all 16 row-loads up-front, 8 independent DPP chains ----
    float4 kr0 = *reinterpret_cast<const float4*>(&k_sh[4 * lane]);
    float4 kr1 = *reinterpret_cast<const float4*>(&k_sh[4 * lane + 256]);
    float4 ra[8], rb[8];
#pragma unroll
    for (int j = 0; j < 8; ++j) {
      const float* kr = &ktL[(size_t)(8 * wave + j) * H_ + 4 * lane];
      ra[j] = *reinterpret_cast<const float4*>(kr);
      rb[j] = *reinterpret_cast<const float4*>(kr + 256);
    }
    float dots[8];
#pragma unroll
    for (int j = 0; j < 8; ++j) {
      float p = ra[j].x * kr0.x + ra[j].y * kr0.y + ra[j].z * kr0.z + ra[j].w * kr0.w
              + rb[j].x * kr1.x + rb[j].y * kr1.y + rb[j].z * kr1.z + rb[j].w * kr1.w;
      dots[j] = wave_sum_dpp(p);
    }
    if (lane == 63) {
#pragma unroll
      for (int j = 0; j < 8; ++j) c_sh[8 * wave + j] = CSCALE * dots[j];
    }
    __syncthreads();                                // B2

    // ---- Phase C: branch-free ikv = sum_s c_s * vq[s] ----
    float p0 = 0.f, p1 = 0.f, p2 = 0.f, p3 = 0.f;
#pragma unroll
    for (int q = 0; q < 16; ++q) {
      float4 c4 = *reinterpret_cast<const float4*>(&c_sh[4 * q]);
      p0 += c4.x * vq[4 * q + 0];
      p1 += c4.y * vq[4 * q + 1];
      p2 += c4.z * vq[4 * q + 2];
      p3 += c4.w * vq[4 * q + 3];
    }
    float ikv = (p0 + p1) + (p2 + p3);

    vv = ALPHA_F * vv + iv_cur + ikv;
    float v = tanh_fast(vv);
    kt = ALPHA_F * kt + OMD_F * k;
    vt = ALPHA_F * vt + OMD_F * v;

    ktL[(size_t)t * H_ + h] = kt;                   // fenced by next B1

    switch (t) {                                    // vq[t] = vt, compile-time indices
      CASE_SET(0)  CASE_SET(1)  CASE_SET(2)  CASE_SET(3)
      CASE_SET(4)  CASE_SET(5)  CASE_SET(6)  CASE_SET(7)
      CASE_SET(8)  CASE_SET(9)  CASE_SET(10) CASE_SET(11)
      CASE_SET(12) CASE_SET(13) CASE_SET(14) CASE_SET(15)
      CASE_SET(16) CASE_SET(17) CASE_SET(18) CASE_SET(19)
      CASE_SET(20) CASE_SET(21) CASE_SET(22) CASE_SET(23)
      CASE_SET(24) CASE_SET(25) CASE_SET(26) CASE_SET(27)
      CASE_SET(28) CASE_SET(29) CASE_SET(30) CASE_SET(31)
      CASE_SET(32) CASE_SET(33) CASE_SET(34) CASE_SET(35)
      CASE_SET(36) CASE_SET(37) CASE_SET(38) CASE_SET(39)
      CASE_SET(40) CASE_SET(41) CASE_SET(42) CASE_SET(43)
      CASE_SET(44) CASE_SET(45) CASE_SET(46) CASE_SET(47)
      CASE_SET(48) CASE_SET(49) CASE_SET(50) CASE_SET(51)
      CASE_SET(52) CASE_SET(53) CASE_SET(54) CASE_SET(55)
      CASE_SET(56) CASE_SET(57) CASE_SET(58) CASE_SET(59)
      CASE_SET(60) CASE_SET(61) CASE_SET(62) CASE_SET(63)
    }

    v_r = v; kt_r = kt; vt_r = vt;                  // stored after next B1
    ik_cur = ik_nxt;
    iv_cur = iv_nxt;
  }

  // final step's deferred stores
  vb2[(size_t)(T_ - 1) * H_] = v_r;
  ktb[(size_t)(T_ - 1) * H_] = kt_r;
  vtb[(size_t)(T_ - 1) * H_] = vt_r;
}

// ---------------- Kernel 3: mem = ETA * vt_hist^T @ kt_hist (per batch, K=T=64) ----------------
__global__ __launch_bounds__(256) void mem_gemm(const float* __restrict__ vtg,
                                                const float* __restrict__ ktg,
                                                float* __restrict__ mem) {
  const int b = blockIdx.z;
  const int i0 = blockIdx.y * 64;
  const int j0 = blockIdx.x * 64;
  __shared__ float Vs[64][65];  // [t][i]
  __shared__ float Ks[64][65];  // [t][j]
  const int tid = threadIdx.x;
  const int ty = tid >> 4, tx = tid & 15;
  const float* vb = vtg + (size_t)b * T_ * H_;
  const float* kb = ktg + (size_t)b * T_ * H_;
#pragma unroll
  for (int e = 0; e < 16; ++e) {
    int idx = tid + e * 256;
    int t = idx >> 6, c = idx & 63;
    Vs[t][c] = vb[(size_t)t * H_ + i0 + c];
    Ks[t][c] = kb[(size_t)t * H_ + j0 + c];
  }
  __syncthreads();
  float acc[4][4] = {};
#pragma unroll 8
  for (int t = 0; t < 64; ++t) {
    float a[4], bb[4];
#pragma unroll
    for (int i = 0; i < 4; ++i) a[i] = Vs[t][ty * 4 + i];
#pragma unroll
    for (int j = 0; j < 4; ++j) bb[j] = Ks[t][tx * 4 + j];
#pragma unroll
    for (int i = 0; i < 4; ++i)
#pragma unroll
      for (int j = 0; j < 4; ++j) acc[i][j] += a[i] * bb[j];
  }
  float* mb = mem + (size_t)b * H_ * H_;
#pragma unroll
  for (int i = 0; i < 4; ++i) {
    float4 o = make_float4(ETA_F * acc[i][0], ETA_F * acc[i][1],
                           ETA_F * acc[i][2], ETA_F * acc[i][3]);
    *reinterpret_cast<float4*>(&mb[(size_t)(i0 + ty * 4 + i) * H_ + j0 + tx * 4]) = o;
  }
}

extern "C" void kernel_launch(void* const* d_in, const int* in_sizes, int n_in,
                              void* d_out, int out_size, void* d_ws, size_t ws_size,
                              hipStream_t stream) {
  const float* x = (const float*)d_in[0];   // (B,T,I)
  const float* W = (const float*)d_in[1];   // (2H,I)
  float* out = (float*)d_out;
  float* mem  = out;                             // B*H*H
  float* keys = out + (size_t)B_ * H_ * H_;      // B*T*H
  float* vals = keys + (size_t)B_ * T_ * H_;

  // proj parked in mem region; consumed by scan before mem_gemm overwrites it.
  float* proj = mem;
  float* ktg = (float*)d_ws;
  float* vtg = ktg + (size_t)B_ * T_ * H_;

  static int lds_bytes = 133376;
  (void)hipFuncSetAttribute((const void*)scan_kernel,
                            hipFuncAttributeMaxDynamicSharedMemorySize, lds_bytes);

  proj_gemm<<<dim3(32, 16), 256, 0, stream>>>(x, W, proj);
  scan_kernel<<<dim3(B_), 512, (size_t)lds_bytes, stream>>>(proj, keys, vals, ktg, vtg);
  mem_gemm<<<dim3(8, 8, B_), 256, 0, stream>>>(vtg, ktg, mem);
}

// Round 7
// 133.453 us; speedup vs baseline: 2.2681x; 1.2028x over previous
//
#include <hip/hip_runtime.h>

#define B_ 32
#define T_ 64
#define I_ 256
#define H_ 512

static constexpr float ALPHA_F = 0.951229424500714f;   // exp(-1/20)
static constexpr float OMD_F   = 0.048770575499286f;   // 1 - decay
static constexpr float ETA_F   = 0.1f;
static constexpr float CSCALE  = 0.02f;                // 0.2 * ETA

// ---------------- fast tanh: exact at saturation, ~1e-6 rel elsewhere ----------------
__device__ __forceinline__ float tanh_fast(float x) {
  float xc = fminf(fmaxf(x, -15.f), 15.f);
  float e = __expf(2.f * xc);
  return (e - 1.f) * __builtin_amdgcn_rcpf(e + 1.f);
}

// ---------------- DPP full-wave (64-lane) sum; valid result in lane 63 ----------------
template <int CTRL>
__device__ __forceinline__ float dpp_add(float x) {
  int mv = __builtin_amdgcn_update_dpp(0, __float_as_int(x), CTRL, 0xF, 0xF, true);
  return x + __int_as_float(mv);
}
__device__ __forceinline__ float wave_sum_dpp(float x) {
  x = dpp_add<0x111>(x);  // row_shr:1
  x = dpp_add<0x112>(x);  // row_shr:2
  x = dpp_add<0x114>(x);  // row_shr:4
  x = dpp_add<0x118>(x);  // row_shr:8
  x = dpp_add<0x142>(x);  // row_bcast:15
  x = dpp_add<0x143>(x);  // row_bcast:31 -> lane63 = full 64-lane sum
  return x;
}

// ---------------- Kernel 1: projection GEMM ----------------
__global__ __launch_bounds__(256) void proj_gemm(const float* __restrict__ x,
                                                 const float* __restrict__ W,
                                                 float* __restrict__ P) {
  __shared__ float As[64][65];
  __shared__ float Bs[64][65];
  const int m0 = blockIdx.x * 64;
  const int n0 = blockIdx.y * 64;
  const int tid = threadIdx.x;
  const int ty = tid >> 4, tx = tid & 15;
  float acc[4][4] = {};
  for (int k0 = 0; k0 < I_; k0 += 64) {
#pragma unroll
    for (int e = 0; e < 16; ++e) {
      int idx = tid + e * 256;
      int r = idx >> 6, c = idx & 63;
      As[r][c] = x[(size_t)(m0 + r) * I_ + k0 + c];
      Bs[r][c] = W[(size_t)(n0 + r) * I_ + k0 + c];
    }
    __syncthreads();
#pragma unroll 8
    for (int kk = 0; kk < 64; ++kk) {
      float a[4], bb[4];
#pragma unroll
      for (int i = 0; i < 4; ++i) a[i] = As[ty * 4 + i][kk];
#pragma unroll
      for (int j = 0; j < 4; ++j) bb[j] = Bs[tx * 4 + j][kk];
#pragma unroll
      for (int i = 0; i < 4; ++i)
#pragma unroll
        for (int j = 0; j < 4; ++j) acc[i][j] += a[i] * bb[j];
    }
    __syncthreads();
  }
#pragma unroll
  for (int i = 0; i < 4; ++i) {
    float4 o = make_float4(acc[i][0], acc[i][1], acc[i][2], acc[i][3]);
    *reinterpret_cast<float4*>(&P[(size_t)(m0 + ty * 4 + i) * 1024 + n0 + tx * 4]) = o;
  }
}

// ---------------- Kernel 2: k-side scan — parallel over (b,h) ----------------
// kv_t = a*kv + ik_t; k = tanh(kv); kt_t = a*kt + (1-a)*k.  No cross-thread deps.
__global__ __launch_bounds__(256) void kscan_kernel(const float* __restrict__ proj,
                                                    float* __restrict__ keys,
                                                    float* __restrict__ ktg) {
  const int gid = blockIdx.x * 256 + threadIdx.x;
  const int b = gid >> 9;
  const int h = gid & (H_ - 1);
  const float* pkk = proj + (size_t)b * T_ * 1024 + h;
  float* ko  = keys + ((size_t)b * T_) * H_ + h;
  float* kto = ktg  + ((size_t)b * T_) * H_ + h;
  float kvv = 0.f, kt = 0.f;
#pragma unroll 8
  for (int t = 0; t < T_; ++t) {
    float ik = pkk[(size_t)t * 1024];
    kvv = ALPHA_F * kvv + ik;
    float k = tanh_fast(kvv);
    kt = ALPHA_F * kt + OMD_F * k;
    ko[(size_t)t * H_]  = k;
    kto[(size_t)t * H_] = kt;
  }
}

// ---------------- Kernel 3: dots GEMM — C[b][t][s] = 0.02 * (k_t . kt_s) ----------------
// One wave per (b,t); k_t held in regs; kt rows streamed from L1/L2; DPP reduce.
__global__ __launch_bounds__(512) void dots_kernel(const float* __restrict__ keys,
                                                   const float* __restrict__ ktg,
                                                   float* __restrict__ C) {
  const int b = blockIdx.y;
  const int t = blockIdx.x * 8 + (threadIdx.x >> 6);
  const int lane = threadIdx.x & 63;
  const float* krow = keys + ((size_t)b * T_ + t) * H_ + 4 * lane;
  float4 k0 = *reinterpret_cast<const float4*>(krow);
  float4 k1 = *reinterpret_cast<const float4*>(krow + 256);
  const float* tb = ktg + (size_t)b * T_ * H_ + 4 * lane;
  float* Cb = C + ((size_t)b * T_ + t) * T_;
#pragma unroll 8
  for (int s = 0; s < T_; ++s) {
    const float* ar = tb + (size_t)s * H_;
    float4 a0 = *reinterpret_cast<const float4*>(ar);
    float4 a1 = *reinterpret_cast<const float4*>(ar + 256);
    float p = a0.x * k0.x + a0.y * k0.y + a0.z * k0.z + a0.w * k0.w
            + a1.x * k1.x + a1.y * k1.y + a1.z * k1.z + a1.w * k1.w;
    p = wave_sum_dpp(p);
    if (lane == 63) Cb[s] = CSCALE * p;
  }
}

// ---------------- Kernel 4: v-side scan — parallel over (b,h), C broadcast from LDS ----------------
// vv_t = a*vv + iv_t + sum_s C[t][s]*vq[s]; v=tanh; vt_t = a*vt + (1-a)*v.
#define CASE_SET(S) case S: vq[S] = vt; break;
__global__ __launch_bounds__(256) void vscan_kernel(const float* __restrict__ proj,
                                                    const float* __restrict__ C,
                                                    float* __restrict__ vals,
                                                    float* __restrict__ vtg) {
  __shared__ float Cs[T_][T_];   // 16 KB
  const int b = blockIdx.x >> 1;
  const int h = ((blockIdx.x & 1) << 8) + threadIdx.x;

  const float* Cb = C + (size_t)b * T_ * T_;
#pragma unroll
  for (int e = 0; e < 4; ++e) {
    int f4 = threadIdx.x + (e << 8);   // 1024 float4s total
    reinterpret_cast<float4*>(Cs)[f4] = reinterpret_cast<const float4*>(Cb)[f4];
  }
  __syncthreads();

  const float* pv = proj + (size_t)b * T_ * 1024 + 512 + h;
  float* vo  = vals + ((size_t)b * T_) * H_ + h;
  float* vto = vtg  + ((size_t)b * T_) * H_ + h;

  float vv = 0.f, vt = 0.f;
  float vq[T_];
#pragma unroll
  for (int s = 0; s < T_; ++s) vq[s] = 0.f;

  float iv_cur = pv[0];
  for (int t = 0; t < T_; ++t) {
    float iv_nxt = (t + 1 < T_) ? pv[(size_t)(t + 1) * 1024] : 0.f;

    float p0 = 0.f, p1 = 0.f, p2 = 0.f, p3 = 0.f;
#pragma unroll
    for (int q = 0; q < 16; ++q) {
      float4 c4 = *reinterpret_cast<const float4*>(&Cs[t][4 * q]);  // broadcast
      p0 += c4.x * vq[4 * q + 0];
      p1 += c4.y * vq[4 * q + 1];
      p2 += c4.z * vq[4 * q + 2];
      p3 += c4.w * vq[4 * q + 3];
    }
    float ikv = (p0 + p1) + (p2 + p3);

    vv = ALPHA_F * vv + iv_cur + ikv;
    float v = tanh_fast(vv);
    vt = ALPHA_F * vt + OMD_F * v;

    switch (t) {                       // vq[t] = vt, compile-time indices only
      CASE_SET(0)  CASE_SET(1)  CASE_SET(2)  CASE_SET(3)
      CASE_SET(4)  CASE_SET(5)  CASE_SET(6)  CASE_SET(7)
      CASE_SET(8)  CASE_SET(9)  CASE_SET(10) CASE_SET(11)
      CASE_SET(12) CASE_SET(13) CASE_SET(14) CASE_SET(15)
      CASE_SET(16) CASE_SET(17) CASE_SET(18) CASE_SET(19)
      CASE_SET(20) CASE_SET(21) CASE_SET(22) CASE_SET(23)
      CASE_SET(24) CASE_SET(25) CASE_SET(26) CASE_SET(27)
      CASE_SET(28) CASE_SET(29) CASE_SET(30) CASE_SET(31)
      CASE_SET(32) CASE_SET(33) CASE_SET(34) CASE_SET(35)
      CASE_SET(36) CASE_SET(37) CASE_SET(38) CASE_SET(39)
      CASE_SET(40) CASE_SET(41) CASE_SET(42) CASE_SET(43)
      CASE_SET(44) CASE_SET(45) CASE_SET(46) CASE_SET(47)
      CASE_SET(48) CASE_SET(49) CASE_SET(50) CASE_SET(51)
      CASE_SET(52) CASE_SET(53) CASE_SET(54) CASE_SET(55)
      CASE_SET(56) CASE_SET(57) CASE_SET(58) CASE_SET(59)
      CASE_SET(60) CASE_SET(61) CASE_SET(62) CASE_SET(63)
    }

    vo[(size_t)t * H_]  = v;
    vto[(size_t)t * H_] = vt;
    iv_cur = iv_nxt;
  }
}

// ---------------- Kernel 5: mem = ETA * vt_hist^T @ kt_hist (per batch, K=T=64) ----------------
__global__ __launch_bounds__(256) void mem_gemm(const float* __restrict__ vtg,
                                                const float* __restrict__ ktg,
                                                float* __restrict__ mem) {
  const int b = blockIdx.z;
  const int i0 = blockIdx.y * 64;
  const int j0 = blockIdx.x * 64;
  __shared__ float Vs[64][65];
  __shared__ float Ks[64][65];
  const int tid = threadIdx.x;
  const int ty = tid >> 4, tx = tid & 15;
  const float* vb = vtg + (size_t)b * T_ * H_;
  const float* kb = ktg + (size_t)b * T_ * H_;
#pragma unroll
  for (int e = 0; e < 16; ++e) {
    int idx = tid + e * 256;
    int t = idx >> 6, c = idx & 63;
    Vs[t][c] = vb[(size_t)t * H_ + i0 + c];
    Ks[t][c] = kb[(size_t)t * H_ + j0 + c];
  }
  __syncthreads();
  float acc[4][4] = {};
#pragma unroll 8
  for (int t = 0; t < 64; ++t) {
    float a[4], bb[4];
#pragma unroll
    for (int i = 0; i < 4; ++i) a[i] = Vs[t][ty * 4 + i];
#pragma unroll
    for (int j = 0; j < 4; ++j) bb[j] = Ks[t][tx * 4 + j];
#pragma unroll
    for (int i = 0; i < 4; ++i)
#pragma unroll
      for (int j = 0; j < 4; ++j) acc[i][j] += a[i] * bb[j];
  }
  float* mb = mem + (size_t)b * H_ * H_;
#pragma unroll
  for (int i = 0; i < 4; ++i) {
    float4 o = make_float4(ETA_F * acc[i][0], ETA_F * acc[i][1],
                           ETA_F * acc[i][2], ETA_F * acc[i][3]);
    *reinterpret_cast<float4*>(&mb[(size_t)(i0 + ty * 4 + i) * H_ + j0 + tx * 4]) = o;
  }
}

extern "C" void kernel_launch(void* const* d_in, const int* in_sizes, int n_in,
                              void* d_out, int out_size, void* d_ws, size_t ws_size,
                              hipStream_t stream) {
  const float* x = (const float*)d_in[0];   // (B,T,I)
  const float* W = (const float*)d_in[1];   // (2H,I)
  float* out = (float*)d_out;
  float* mem  = out;                             // B*H*H = 8M floats (32 MB)
  float* keys = out + (size_t)B_ * H_ * H_;      // B*T*H
  float* vals = keys + (size_t)B_ * T_ * H_;

  // Scratch parked in the mem region (overwritten last by mem_gemm):
  //   proj: [0, 8MB) ; C: [16MB, 16.5MB)
  float* proj = mem;
  float* Cbuf = mem + (size_t)4 * 1024 * 1024;
  // fp32 kt/vt history in workspace (8 MB)
  float* ktg = (float*)d_ws;
  float* vtg = ktg + (size_t)B_ * T_ * H_;

  proj_gemm<<<dim3(32, 16), 256, 0, stream>>>(x, W, proj);
  kscan_kernel<<<dim3(B_ * H_ / 256), 256, 0, stream>>>(proj, keys, ktg);
  dots_kernel<<<dim3(8, B_), 512, 0, stream>>>(keys, ktg, Cbuf);
  vscan_kernel<<<dim3(2 * B_), 256, 0, stream>>>(proj, Cbuf, vals, vtg);
  mem_gemm<<<dim3(8, 8, B_), 256, 0, stream>>>(vtg, ktg, mem);
}

// Round 8
// 113.267 us; speedup vs baseline: 2.6724x; 1.1782x over previous
//
#include <hip/hip_runtime.h>

#define B_ 32
#define T_ 64
#define I_ 256
#define H_ 512

static constexpr float ALPHA_F = 0.951229424500714f;   // exp(-1/20)
static constexpr float OMD_F   = 0.048770575499286f;   // 1 - decay
static constexpr float ETA_F   = 0.1f;
static constexpr float CSCALE  = 0.02f;                // 0.2 * ETA

// ---------------- fast tanh: exact at saturation, ~1e-6 rel elsewhere ----------------
__device__ __forceinline__ float tanh_fast(float x) {
  float xc = fminf(fmaxf(x, -15.f), 15.f);
  float e = __expf(2.f * xc);
  return (e - 1.f) * __builtin_amdgcn_rcpf(e + 1.f);
}

// ---------------- DPP full-wave (64-lane) sum; valid result in lane 63 ----------------
template <int CTRL>
__device__ __forceinline__ float dpp_add(float x) {
  int mv = __builtin_amdgcn_update_dpp(0, __float_as_int(x), CTRL, 0xF, 0xF, true);
  return x + __int_as_float(mv);
}
__device__ __forceinline__ float wave_sum_dpp(float x) {
  x = dpp_add<0x111>(x);  // row_shr:1
  x = dpp_add<0x112>(x);  // row_shr:2
  x = dpp_add<0x114>(x);  // row_shr:4
  x = dpp_add<0x118>(x);  // row_shr:8
  x = dpp_add<0x142>(x);  // row_bcast:15
  x = dpp_add<0x143>(x);  // row_bcast:31 -> lane63 = full 64-lane sum
  return x;
}

// ---------------- Kernel 1: projection GEMM ----------------
__global__ __launch_bounds__(256) void proj_gemm(const float* __restrict__ x,
                                                 const float* __restrict__ W,
                                                 float* __restrict__ P) {
  __shared__ float As[64][65];
  __shared__ float Bs[64][65];
  const int m0 = blockIdx.x * 64;
  const int n0 = blockIdx.y * 64;
  const int tid = threadIdx.x;
  const int ty = tid >> 4, tx = tid & 15;
  float acc[4][4] = {};
  for (int k0 = 0; k0 < I_; k0 += 64) {
#pragma unroll
    for (int e = 0; e < 16; ++e) {
      int idx = tid + e * 256;
      int r = idx >> 6, c = idx & 63;
      As[r][c] = x[(size_t)(m0 + r) * I_ + k0 + c];
      Bs[r][c] = W[(size_t)(n0 + r) * I_ + k0 + c];
    }
    __syncthreads();
#pragma unroll 8
    for (int kk = 0; kk < 64; ++kk) {
      float a[4], bb[4];
#pragma unroll
      for (int i = 0; i < 4; ++i) a[i] = As[ty * 4 + i][kk];
#pragma unroll
      for (int j = 0; j < 4; ++j) bb[j] = Bs[tx * 4 + j][kk];
#pragma unroll
      for (int i = 0; i < 4; ++i)
#pragma unroll
        for (int j = 0; j < 4; ++j) acc[i][j] += a[i] * bb[j];
    }
    __syncthreads();
  }
#pragma unroll
  for (int i = 0; i < 4; ++i) {
    float4 o = make_float4(acc[i][0], acc[i][1], acc[i][2], acc[i][3]);
    *reinterpret_cast<float4*>(&P[(size_t)(m0 + ty * 4 + i) * 1024 + n0 + tx * 4]) = o;
  }
}

// ---------------- Kernel 2: k-side scan — parallel over (b,h) ----------------
__global__ __launch_bounds__(256) void kscan_kernel(const float* __restrict__ proj,
                                                    float* __restrict__ keys,
                                                    float* __restrict__ ktg) {
  const int gid = blockIdx.x * 256 + threadIdx.x;
  const int b = gid >> 9;
  const int h = gid & (H_ - 1);
  const float* pkk = proj + (size_t)b * T_ * 1024 + h;
  float* ko  = keys + ((size_t)b * T_) * H_ + h;
  float* kto = ktg  + ((size_t)b * T_) * H_ + h;
  float kvv = 0.f, kt = 0.f;
#pragma unroll 8
  for (int t = 0; t < T_; ++t) {
    float ik = pkk[(size_t)t * 1024];
    kvv = ALPHA_F * kvv + ik;
    float k = tanh_fast(kvv);
    kt = ALPHA_F * kt + OMD_F * k;
    ko[(size_t)t * H_]  = k;
    kto[(size_t)t * H_] = kt;
  }
}

// ---------------- Kernel 3: dots GEMM — C[b][t][s] = 0.02 * (k_t . kt_s) ----------------
__global__ __launch_bounds__(512) void dots_kernel(const float* __restrict__ keys,
                                                   const float* __restrict__ ktg,
                                                   float* __restrict__ C) {
  const int b = blockIdx.y;
  const int t = blockIdx.x * 8 + (threadIdx.x >> 6);
  const int lane = threadIdx.x & 63;
  const float* krow = keys + ((size_t)b * T_ + t) * H_ + 4 * lane;
  float4 k0 = *reinterpret_cast<const float4*>(krow);
  float4 k1 = *reinterpret_cast<const float4*>(krow + 256);
  const float* tb = ktg + (size_t)b * T_ * H_ + 4 * lane;
  float* Cb = C + ((size_t)b * T_ + t) * T_;
#pragma unroll 8
  for (int s = 0; s < T_; ++s) {
    const float* ar = tb + (size_t)s * H_;
    float4 a0 = *reinterpret_cast<const float4*>(ar);
    float4 a1 = *reinterpret_cast<const float4*>(ar + 256);
    float p = a0.x * k0.x + a0.y * k0.y + a0.z * k0.z + a0.w * k0.w
            + a1.x * k1.x + a1.y * k1.y + a1.z * k1.z + a1.w * k1.w;
    p = wave_sum_dpp(p);
    if (lane == 63) Cb[s] = CSCALE * p;
  }
}

// ---------------- Kernel 4: v-side scan — 1 wave/block, all state in registers ----------------
// vv_t = a*vv + iv_t + sum_s C[t][s]*vt_s[h]; v=tanh(vv); vt_t = a*vt + (1-a)*v.
// vt history: float4 vqv[16] (SROA-friendly, all accesses compile-time).
// C rows: LDS-staged once, register ping-pong prefetch (ca/cbuf).
#define CASE4(Q) \
  case 4*Q+0: vqv[Q].x = vt; break; \
  case 4*Q+1: vqv[Q].y = vt; break; \
  case 4*Q+2: vqv[Q].z = vt; break; \
  case 4*Q+3: vqv[Q].w = vt; break;

#define VSTEP(T_IDX, CUR, NXT)                                                  \
  {                                                                             \
    const int tt = (T_IDX);                                                     \
    _Pragma("unroll")                                                           \
    for (int q = 0; q < 16; ++q)                                                \
      NXT[q] = *reinterpret_cast<const float4*>(&Cs[(tt + 1) & 63][4 * q]);     \
    float p0 = 0.f, p1 = 0.f, p2 = 0.f, p3 = 0.f;                               \
    _Pragma("unroll")                                                           \
    for (int q = 0; q < 16; ++q) {                                              \
      p0 += CUR[q].x * vqv[q].x;                                                \
      p1 += CUR[q].y * vqv[q].y;                                                \
      p2 += CUR[q].z * vqv[q].z;                                                \
      p3 += CUR[q].w * vqv[q].w;                                                \
    }                                                                           \
    float ikv = (p0 + p1) + (p2 + p3);                                          \
    float ivc = iv0; iv0 = iv1;                                                 \
    iv1 = (tt + 2 < T_) ? pv[(size_t)(tt + 2) * 1024] : 0.f;                    \
    vv = ALPHA_F * vv + ivc + ikv;                                              \
    float v = tanh_fast(vv);                                                    \
    vt = ALPHA_F * vt + OMD_F * v;                                              \
    switch (tt) {                                                               \
      CASE4(0)  CASE4(1)  CASE4(2)  CASE4(3)                                    \
      CASE4(4)  CASE4(5)  CASE4(6)  CASE4(7)                                    \
      CASE4(8)  CASE4(9)  CASE4(10) CASE4(11)                                   \
      CASE4(12) CASE4(13) CASE4(14) CASE4(15)                                   \
    }                                                                           \
    vo[(size_t)tt * H_]  = v;                                                   \
    vto[(size_t)tt * H_] = vt;                                                  \
  }

__global__ __launch_bounds__(64, 1) void vscan_kernel(const float* __restrict__ proj,
                                                      const float* __restrict__ C,
                                                      float* __restrict__ vals,
                                                      float* __restrict__ vtg) {
  __shared__ float Cs[T_][T_];   // 16 KB
  const int b    = blockIdx.x >> 3;
  const int lane = threadIdx.x;                 // 0..63
  const int h    = ((blockIdx.x & 7) << 6) + lane;

  const float* Cb = C + (size_t)b * T_ * T_;
#pragma unroll
  for (int e = 0; e < 16; ++e)
    reinterpret_cast<float4*>(&Cs[0][0])[lane + (e << 6)] =
        reinterpret_cast<const float4*>(Cb)[lane + (e << 6)];

  const float* pv = proj + (size_t)b * T_ * 1024 + 512 + h;
  float* vo  = vals + ((size_t)b * T_) * H_ + h;
  float* vto = vtg  + ((size_t)b * T_) * H_ + h;

  float vv = 0.f, vt = 0.f;
  float4 vqv[16];
#pragma unroll
  for (int q = 0; q < 16; ++q) vqv[q] = make_float4(0.f, 0.f, 0.f, 0.f);

  float iv0 = pv[0];
  float iv1 = pv[1024];

  __syncthreads();   // Cs ready

  float4 ca[16], cbuf[16];
#pragma unroll
  for (int q = 0; q < 16; ++q)
    ca[q] = *reinterpret_cast<const float4*>(&Cs[0][4 * q]);

  for (int t2 = 0; t2 < T_; t2 += 2) {
    VSTEP(t2,     ca,   cbuf)
    VSTEP(t2 + 1, cbuf, ca)
  }
}

// ---------------- Kernel 5: mem = ETA * vt_hist^T @ kt_hist (per batch, K=T=64) ----------------
__global__ __launch_bounds__(256) void mem_gemm(const float* __restrict__ vtg,
                                                const float* __restrict__ ktg,
                                                float* __restrict__ mem) {
  const int b = blockIdx.z;
  const int i0 = blockIdx.y * 64;
  const int j0 = blockIdx.x * 64;
  __shared__ float Vs[64][65];
  __shared__ float Ks[64][65];
  const int tid = threadIdx.x;
  const int ty = tid >> 4, tx = tid & 15;
  const float* vb = vtg + (size_t)b * T_ * H_;
  const float* kb = ktg + (size_t)b * T_ * H_;
#pragma unroll
  for (int e = 0; e < 16; ++e) {
    int idx = tid + e * 256;
    int t = idx >> 6, c = idx & 63;
    Vs[t][c] = vb[(size_t)t * H_ + i0 + c];
    Ks[t][c] = kb[(size_t)t * H_ + j0 + c];
  }
  __syncthreads();
  float acc[4][4] = {};
#pragma unroll 8
  for (int t = 0; t < 64; ++t) {
    float a[4], bb[4];
#pragma unroll
    for (int i = 0; i < 4; ++i) a[i] = Vs[t][ty * 4 + i];
#pragma unroll
    for (int j = 0; j < 4; ++j) bb[j] = Ks[t][tx * 4 + j];
#pragma unroll
    for (int i = 0; i < 4; ++i)
#pragma unroll
      for (int j = 0; j < 4; ++j) acc[i][j] += a[i] * bb[j];
  }
  float* mb = mem + (size_t)b * H_ * H_;
#pragma unroll
  for (int i = 0; i < 4; ++i) {
    float4 o = make_float4(ETA_F * acc[i][0], ETA_F * acc[i][1],
                           ETA_F * acc[i][2], ETA_F * acc[i][3]);
    *reinterpret_cast<float4*>(&mb[(size_t)(i0 + ty * 4 + i) * H_ + j0 + tx * 4]) = o;
  }
}

extern "C" void kernel_launch(void* const* d_in, const int* in_sizes, int n_in,
                              void* d_out, int out_size, void* d_ws, size_t ws_size,
                              hipStream_t stream) {
  const float* x = (const float*)d_in[0];   // (B,T,I)
  const float* W = (const float*)d_in[1];   // (2H,I)
  float* out = (float*)d_out;
  float* mem  = out;                             // B*H*H
  float* keys = out + (size_t)B_ * H_ * H_;      // B*T*H
  float* vals = keys + (size_t)B_ * T_ * H_;

  // Scratch parked in the mem region (overwritten last by mem_gemm):
  //   proj: [0, 8MB) ; C: [16MB, 16.5MB)
  float* proj = mem;
  float* Cbuf = mem + (size_t)4 * 1024 * 1024;
  float* ktg = (float*)d_ws;
  float* vtg = ktg + (size_t)B_ * T_ * H_;

  proj_gemm<<<dim3(32, 16), 256, 0, stream>>>(x, W, proj);
  kscan_kernel<<<dim3(B_ * H_ / 256), 256, 0, stream>>>(proj, keys, ktg);
  dots_kernel<<<dim3(8, B_), 512, 0, stream>>>(keys, ktg, Cbuf);
  vscan_kernel<<<dim3(8 * B_), 64, 0, stream>>>(proj, Cbuf, vals, vtg);
  mem_gemm<<<dim3(8, 8, B_), 256, 0, stream>>>(vtg, ktg, mem);
}